// Round 14
// baseline (237.199 us; speedup 1.0000x reference)
//
#include <hip/hip_runtime.h>
#include <hip/hip_fp16.h>

// GraphSAGE (mean agg), 3 layers + linear head, fp32 accum, fp16 transport.
// R14: layer/act kernels go 16 threads/node (4 parities x 4 col-slices,
// 8 nodes per 128-thr block). Each parity-thread now walks deg/4 ~ 4 edges =
// ONE 4-deep load round (was 2+tail at 8 thr/node), and the GEMV K-loop
// splits 4 ways (12 k's/thread). Extra shfl_xor(8) combine level is cheap.
// Rationale: gather resisted bytes (R9), traffic (R10), ILP/occ (R11),
// divergence (R12) -> remaining lever is the dependent-round critical path
// (p-array spans 8 non-coherent XCD L2s -> L3-class ~500cyc rounds).
// K0 unchanged: fill (~46us atomic floor) + single-pass dual GEMM in shadow.

constexpr int HID = 48;
constexpr int MAXDEG = 64;
constexpr int GNB = 64;  // nodes per K0 proj block

__device__ __forceinline__ unsigned pack_h2(float a, float b) {
    __half2 h = __floats2half2_rn(a, b);
    return *reinterpret_cast<unsigned*>(&h);
}
__device__ __forceinline__ void acc_u2(float* g, uint2 u) {
    __half2 h0 = *reinterpret_cast<__half2*>(&u.x);
    __half2 h1 = *reinterpret_cast<__half2*>(&u.y);
    float2 f0 = __half22float2(h0), f1 = __half22float2(h1);
    g[0] += f0.x; g[1] += f0.y; g[2] += f1.x; g[3] += f1.y;
}
__device__ __forceinline__ void unpack_u2(float* v, uint2 u) {
    __half2 h0 = *reinterpret_cast<__half2*>(&u.x);
    __half2 h1 = *reinterpret_cast<__half2*>(&u.y);
    float2 f0 = __half22float2(h0), f1 = __half22float2(h1);
    v[0] = f0.x; v[1] = f0.y; v[2] = f1.x; v[3] = f1.y;
}
__device__ __forceinline__ void fma12_h(const uint2* __restrict__ wrow, float s,
                                        float* acc) {
    uint2 w0 = wrow[0], w1 = wrow[1], w2 = wrow[2];
    float v[12];
    unpack_u2(v + 0, w0); unpack_u2(v + 4, w1); unpack_u2(v + 8, w2);
#pragma unroll
    for (int j = 0; j < 12; ++j) acc[j] = fmaf(s, v[j], acc[j]);
}

// gather edges i == e (mod 4), 4 rows in flight, slice jb; combine the 4
// parities via shfl_xor(4) + shfl_xor(8) -> full neighbor-sum in g[12].
__device__ __forceinline__ void gather_h16(const __half* __restrict__ p,
                                           const unsigned short* __restrict__ bkt,
                                           int deg, int e, int jb, float* g) {
    float ga[12], gb[12];
#pragma unroll
    for (int j = 0; j < 12; ++j) { ga[j] = 0.0f; gb[j] = 0.0f; }
    int i = e;
    for (; i + 12 < deg; i += 16) {
        int s0 = bkt[i], s1 = bkt[i + 4], s2 = bkt[i + 8], s3 = bkt[i + 12];
        const uint2* r0 = reinterpret_cast<const uint2*>(p + (size_t)s0 * HID + jb);
        const uint2* r1 = reinterpret_cast<const uint2*>(p + (size_t)s1 * HID + jb);
        const uint2* r2 = reinterpret_cast<const uint2*>(p + (size_t)s2 * HID + jb);
        const uint2* r3 = reinterpret_cast<const uint2*>(p + (size_t)s3 * HID + jb);
        uint2 a0 = r0[0], a1 = r0[1], a2 = r0[2];
        uint2 b0 = r1[0], b1 = r1[1], b2 = r1[2];
        uint2 c0 = r2[0], c1 = r2[1], c2 = r2[2];
        uint2 d0 = r3[0], d1 = r3[1], d2 = r3[2];
        acc_u2(ga + 0, a0); acc_u2(ga + 4, a1); acc_u2(ga + 8, a2);
        acc_u2(gb + 0, b0); acc_u2(gb + 4, b1); acc_u2(gb + 8, b2);
        acc_u2(ga + 0, c0); acc_u2(ga + 4, c1); acc_u2(ga + 8, c2);
        acc_u2(gb + 0, d0); acc_u2(gb + 4, d1); acc_u2(gb + 8, d2);
    }
    for (; i + 4 < deg; i += 8) {
        int s0 = bkt[i], s1 = bkt[i + 4];
        const uint2* r0 = reinterpret_cast<const uint2*>(p + (size_t)s0 * HID + jb);
        const uint2* r1 = reinterpret_cast<const uint2*>(p + (size_t)s1 * HID + jb);
        uint2 a0 = r0[0], a1 = r0[1], a2 = r0[2];
        uint2 b0 = r1[0], b1 = r1[1], b2 = r1[2];
        acc_u2(ga + 0, a0); acc_u2(ga + 4, a1); acc_u2(ga + 8, a2);
        acc_u2(gb + 0, b0); acc_u2(gb + 4, b1); acc_u2(gb + 8, b2);
    }
    if (i < deg) {
        const uint2* r0 = reinterpret_cast<const uint2*>(p + (size_t)bkt[i] * HID + jb);
        uint2 a0 = r0[0], a1 = r0[1], a2 = r0[2];
        acc_u2(ga + 0, a0); acc_u2(ga + 4, a1); acc_u2(ga + 8, a2);
    }
#pragma unroll
    for (int j = 0; j < 12; ++j) g[j] = ga[j] + gb[j];
#pragma unroll
    for (int j = 0; j < 12; ++j) g[j] += __shfl_xor(g[j], 4, 64);
#pragma unroll
    for (int j = 0; j < 12; ++j) g[j] += __shfl_xor(g[j], 8, 64);
}

// ---- K0: blocks [0,gemm_blocks): single pass, p0=fp16(X@Wn), s0=X@Ws+b,
//      fp16 weights in LDS; blocks [gemm_blocks,..): bucket fill ----
__global__ __launch_bounds__(128) void fill_proj_k(
    const float* __restrict__ X, const float* __restrict__ Wn,
    const float* __restrict__ Ws, const float* __restrict__ bias,
    __half* __restrict__ p_out, float* __restrict__ s_out, int n_nodes,
    const int* __restrict__ src, const int* __restrict__ dst,
    int* __restrict__ cnt, unsigned short* __restrict__ buckets,
    int n_edges, int gemm_blocks) {
    __shared__ uint2 wn_s[96 * HID / 4];   // 9.2 KB packed fp16
    __shared__ uint2 ws_s[96 * HID / 4];   // 9.2 KB
    __shared__ float bias_lds[HID];
    const int t = threadIdx.x;

    if ((int)blockIdx.x >= gemm_blocks) {
        int base = (blockIdx.x - gemm_blocks) * 256 + t;
        int e0 = base, e1 = base + 128;
        if (e0 < n_edges) {
            int d = dst[e0];
            int s = src[e0];
            int pos = atomicAdd(&cnt[d], 1);
            if (pos < MAXDEG) buckets[(size_t)d * MAXDEG + pos] = (unsigned short)s;
        }
        if (e1 < n_edges) {
            int d = dst[e1];
            int s = src[e1];
            int pos = atomicAdd(&cnt[d], 1);
            if (pos < MAXDEG) buckets[(size_t)d * MAXDEG + pos] = (unsigned short)s;
        }
        return;
    }

    for (int i4 = t; i4 < 96 * HID / 4; i4 += 128) {
        float4 a = reinterpret_cast<const float4*>(Wn)[i4];
        float4 b = reinterpret_cast<const float4*>(Ws)[i4];
        wn_s[i4] = make_uint2(pack_h2(a.x, a.y), pack_h2(a.z, a.w));
        ws_s[i4] = make_uint2(pack_h2(b.x, b.y), pack_h2(b.z, b.w));
    }
    if (t < HID) bias_lds[t] = bias[t];
    __syncthreads();

    const int q = t & 3;
    const int m = t >> 2;
    const int jb = q * 12;
    const int q3 = q * 3;
    const int n0 = blockIdx.x * GNB + 2 * m;
    const int n1 = n0 + 1;
    const bool v0 = n0 < n_nodes, v1 = n1 < n_nodes;
    const int cn0 = v0 ? n0 : 0, cn1 = v1 ? n1 : 0;
    const float4* xr0 = reinterpret_cast<const float4*>(X + (size_t)cn0 * 96);
    const float4* xr1 = reinterpret_cast<const float4*>(X + (size_t)cn1 * 96);

    float pa[12], pb[12], sa[12], sb[12];
#pragma unroll
    for (int j = 0; j < 12; ++j) {
        pa[j] = 0.0f; pb[j] = 0.0f;
        float b = bias_lds[jb + j];
        sa[j] = b; sb[j] = b;
    }
#pragma unroll 2
    for (int k4 = 0; k4 < 24; ++k4) {
        float4 xa = xr0[k4];
        float4 xb = xr1[k4];
#pragma unroll
        for (int c = 0; c < 4; ++c) {
            const int k = k4 * 4 + c;
            float x0 = (c == 0) ? xa.x : (c == 1) ? xa.y : (c == 2) ? xa.z : xa.w;
            float x1 = (c == 0) ? xb.x : (c == 1) ? xb.y : (c == 2) ? xb.z : xb.w;
            const uint2* wr = &wn_s[k * 12 + q3];
            const uint2* ur = &ws_s[k * 12 + q3];
            float vn[12], vs[12];
            uint2 w0 = wr[0], w1 = wr[1], w2 = wr[2];
            uint2 u0 = ur[0], u1 = ur[1], u2 = ur[2];
            unpack_u2(vn + 0, w0); unpack_u2(vn + 4, w1); unpack_u2(vn + 8, w2);
            unpack_u2(vs + 0, u0); unpack_u2(vs + 4, u1); unpack_u2(vs + 8, u2);
#pragma unroll
            for (int j = 0; j < 12; ++j) {
                pa[j] = fmaf(x0, vn[j], pa[j]);
                pb[j] = fmaf(x1, vn[j], pb[j]);
                sa[j] = fmaf(x0, vs[j], sa[j]);
                sb[j] = fmaf(x1, vs[j], sb[j]);
            }
        }
    }
    if (v0) {
        uint2* po = reinterpret_cast<uint2*>(p_out + (size_t)n0 * HID + jb);
        po[0] = make_uint2(pack_h2(pa[0], pa[1]), pack_h2(pa[2], pa[3]));
        po[1] = make_uint2(pack_h2(pa[4], pa[5]), pack_h2(pa[6], pa[7]));
        po[2] = make_uint2(pack_h2(pa[8], pa[9]), pack_h2(pa[10], pa[11]));
        float4* so = reinterpret_cast<float4*>(s_out + (size_t)n0 * HID + jb);
        so[0] = make_float4(sa[0], sa[1], sa[2], sa[3]);
        so[1] = make_float4(sa[4], sa[5], sa[6], sa[7]);
        so[2] = make_float4(sa[8], sa[9], sa[10], sa[11]);
    }
    if (v1) {
        uint2* po = reinterpret_cast<uint2*>(p_out + (size_t)n1 * HID + jb);
        po[0] = make_uint2(pack_h2(pb[0], pb[1]), pack_h2(pb[2], pb[3]));
        po[1] = make_uint2(pack_h2(pb[4], pb[5]), pack_h2(pb[6], pb[7]));
        po[2] = make_uint2(pack_h2(pb[8], pb[9]), pack_h2(pb[10], pb[11]));
        float4* so = reinterpret_cast<float4*>(s_out + (size_t)n1 * HID + jb);
        so[0] = make_float4(sb[0], sb[1], sb[2], sb[3]);
        so[1] = make_float4(sb[4], sb[5], sb[6], sb[7]);
        so[2] = make_float4(sb[8], sb[9], sb[10], sb[11]);
    }
}

// ---- K1: h1 = relu(s0 + di * mean-gather(p0)); 16 thr/node, 8 nodes/block ----
__global__ __launch_bounds__(128, 8) void act_k(
    const __half* __restrict__ p_in, const float* __restrict__ s_in,
    const int* __restrict__ cnt, const unsigned short* __restrict__ buckets,
    __half* __restrict__ h_out, int n_nodes) {
    const int t = threadIdx.x;
    const int q = t & 3;
    const int e = (t >> 2) & 3;
    const int m = t >> 4;
    const int n = blockIdx.x * 8 + m;
    if (n >= n_nodes) return;
    const int jb = q * 12;

    const int deg = min(cnt[n], MAXDEG);
    const float di = 1.0f / fmaxf((float)deg, 1.0f);
    float g[12];
    gather_h16(p_in, buckets + (size_t)n * MAXDEG, deg, e, jb, g);

    if (e == 0) {
        const float4* sr = reinterpret_cast<const float4*>(s_in + (size_t)n * HID + jb);
        float h[12];
#pragma unroll
        for (int j4 = 0; j4 < 3; ++j4) {
            float4 sv = sr[j4];
            h[j4 * 4 + 0] = fmaxf(fmaf(di, g[j4 * 4 + 0], sv.x), 0.0f);
            h[j4 * 4 + 1] = fmaxf(fmaf(di, g[j4 * 4 + 1], sv.y), 0.0f);
            h[j4 * 4 + 2] = fmaxf(fmaf(di, g[j4 * 4 + 2], sv.z), 0.0f);
            h[j4 * 4 + 3] = fmaxf(fmaf(di, g[j4 * 4 + 3], sv.w), 0.0f);
        }
        uint2* ho = reinterpret_cast<uint2*>(h_out + (size_t)n * HID + jb);
        ho[0] = make_uint2(pack_h2(h[0], h[1]), pack_h2(h[2], h[3]));
        ho[1] = make_uint2(pack_h2(h[4], h[5]), pack_h2(h[6], h[7]));
        ho[2] = make_uint2(pack_h2(h[8], h[9]), pack_h2(h[10], h[11]));
    }
}

// ---- K2/K3: g = mean-gather(h_in); acc = g@Wn + h_self@Ws + b; 16 thr/node.
// GEMV K-range split 4 ways by parity e (k in [e*12,e*12+12)); slice owner of
// k is quad-thread q'=e within the same (node,parity) group -> shfl.
template <bool LAST>
__global__ __launch_bounds__(128, 6) void layer_k(
    const __half* __restrict__ h_in, const int* __restrict__ cnt,
    const unsigned short* __restrict__ buckets, const float* __restrict__ wn,
    const float* __restrict__ ws, const float* __restrict__ bn,
    const float* __restrict__ w_pred, const float* __restrict__ b_pred,
    __half* __restrict__ h_out, float* __restrict__ out, int n_nodes) {
    __shared__ uint2 wn_s[HID * HID / 4];   // 4.6 KB packed fp16
    __shared__ uint2 ws_s[HID * HID / 4];   // 4.6 KB
    __shared__ float bn_lds[HID];
    __shared__ float wp_lds[HID];

    const int t = threadIdx.x;
    for (int i4 = t; i4 < HID * HID / 4; i4 += 128) {
        float4 a = reinterpret_cast<const float4*>(wn)[i4];
        float4 b = reinterpret_cast<const float4*>(ws)[i4];
        wn_s[i4] = make_uint2(pack_h2(a.x, a.y), pack_h2(a.z, a.w));
        ws_s[i4] = make_uint2(pack_h2(b.x, b.y), pack_h2(b.z, b.w));
    }
    if (t < HID) bn_lds[t] = bn[t];
    if (LAST && t < HID) wp_lds[t] = w_pred[t];
    __syncthreads();

    const int q = t & 3;
    const int e = (t >> 2) & 3;
    const int m = t >> 4;
    const int n = blockIdx.x * 8 + m;
    if (n >= n_nodes) return;
    const int jb = q * 12;

    const int deg = min(cnt[n], MAXDEG);
    const float di = 1.0f / fmaxf((float)deg, 1.0f);
    float g[12];
    gather_h16(h_in, buckets + (size_t)n * MAXDEG, deg, e, jb, g);
#pragma unroll
    for (int j = 0; j < 12; ++j) g[j] *= di;

    float hs_own[12];
    {
        const uint2* hr = reinterpret_cast<const uint2*>(h_in + (size_t)n * HID + jb);
        uint2 a = hr[0], b = hr[1], c = hr[2];
        unpack_u2(hs_own + 0, a); unpack_u2(hs_own + 4, b); unpack_u2(hs_own + 8, c);
    }

    float acc[12];
#pragma unroll
    for (int j = 0; j < 12; ++j) acc[j] = (e == 0) ? bn_lds[jb + j] : 0.0f;

    // K-range [e*12, e*12+12): slice owner q'=e within same (m,e) quad group
    const int srcl = (t & ~3) | e;
#pragma unroll
    for (int kk = 0; kk < 12; ++kk) {
        const int k = e * 12 + kk;
        float gs = __shfl(g[kk], srcl, 64);
        float hv = __shfl(hs_own[kk], srcl, 64);
        fma12_h(&wn_s[(k * HID + jb) >> 2], gs, acc);
        fma12_h(&ws_s[(k * HID + jb) >> 2], hv, acc);
    }
#pragma unroll
    for (int j = 0; j < 12; ++j) {
        acc[j] += __shfl_xor(acc[j], 4, 64);
        acc[j] += __shfl_xor(acc[j], 8, 64);
    }

    if (LAST) {
        float s = 0.0f;
#pragma unroll
        for (int j = 0; j < 12; ++j) s = fmaf(fmaxf(acc[j], 0.0f), wp_lds[jb + j], s);
        s += __shfl_xor(s, 1, 64);
        s += __shfl_xor(s, 2, 64);
        if ((t & 15) == 0) out[n] = s + b_pred[0];
        return;
    }

    if (e == 0) {
        float h[12];
#pragma unroll
        for (int j = 0; j < 12; ++j) h[j] = fmaxf(acc[j], 0.0f);
        uint2* ho = reinterpret_cast<uint2*>(h_out + (size_t)n * HID + jb);
        ho[0] = make_uint2(pack_h2(h[0], h[1]), pack_h2(h[2], h[3]));
        ho[1] = make_uint2(pack_h2(h[4], h[5]), pack_h2(h[6], h[7]));
        ho[2] = make_uint2(pack_h2(h[8], h[9]), pack_h2(h[10], h[11]));
    }
}

extern "C" void kernel_launch(void* const* d_in, const int* in_sizes, int n_in,
                              void* d_out, int out_size, void* d_ws, size_t ws_size,
                              hipStream_t stream) {
    const float* x        = (const float*)d_in[0];
    const int*   ei       = (const int*)d_in[1];
    const float* w_self0  = (const float*)d_in[2];
    const float* w_neigh0 = (const float*)d_in[3];
    const float* b0       = (const float*)d_in[4];
    const float* w_self1  = (const float*)d_in[5];
    const float* w_neigh1 = (const float*)d_in[6];
    const float* b1       = (const float*)d_in[7];
    const float* w_self2  = (const float*)d_in[8];
    const float* w_neigh2 = (const float*)d_in[9];
    const float* b2       = (const float*)d_in[10];
    const float* w_pred   = (const float*)d_in[11];
    const float* b_pred   = (const float*)d_in[12];

    const int n_nodes = in_sizes[0] / 96;
    const int n_edges = in_sizes[1] / 2;
    const int* src = ei;
    const int* dst = ei + n_edges;

    // workspace layout
    char* wsb = (char*)d_ws;
    int* cnt                = (int*)wsb;              wsb += (size_t)n_nodes * 4;
    unsigned short* buckets = (unsigned short*)wsb;   wsb += (size_t)n_nodes * MAXDEG * 2;
    __half* p0 = (__half*)wsb;                        wsb += (size_t)n_nodes * HID * 2;
    __half* h1 = (__half*)wsb;                        wsb += (size_t)n_nodes * HID * 2;
    __half* h2 = (__half*)wsb;                        wsb += (size_t)n_nodes * HID * 2;
    float* s0 = (float*)wsb;                          wsb += (size_t)n_nodes * HID * 4;
    float* out = (float*)d_out;

    const int gnb = (n_nodes + GNB - 1) / GNB;        // 782 proj blocks
    const int fb = (n_edges + 255) / 256;             // 3125 fill blocks
    const int lb = (n_nodes + 7) / 8;                 // 6250 layer blocks

    hipMemsetAsync(cnt, 0, (size_t)n_nodes * 4, stream);

    // K0: fill + p0(fp16), s0 (single pass, fp16 weights)
    fill_proj_k<<<gnb + fb, 128, 0, stream>>>(x, w_neigh0, w_self0, b0, p0, s0,
                                              n_nodes, src, dst, cnt, buckets,
                                              n_edges, gnb);
    // K1: h1 = relu(s0 + di*gather(p0))
    act_k<<<lb, 128, 0, stream>>>(p0, s0, cnt, buckets, h1, n_nodes);
    // K2: layer 1 -> h2
    layer_k<false><<<lb, 128, 0, stream>>>(h1, cnt, buckets, w_neigh1, w_self1,
                                           b1, nullptr, nullptr, h2, nullptr,
                                           n_nodes);
    // K3: layer 2 + head -> out
    layer_k<true><<<lb, 128, 0, stream>>>(h2, cnt, buckets, w_neigh2, w_self2,
                                          b2, w_pred, b_pred, nullptr, out,
                                          n_nodes);
}

// Round 15
// 211.749 us; speedup vs baseline: 1.1202x; 1.1202x over previous
//
#include <hip/hip_runtime.h>
#include <hip/hip_fp16.h>

// GraphSAGE (mean agg), 3 layers + linear head, fp32 accum, fp16 transport.
// R15: revert R14's 16-thr/node split (237us: extra shfl levels + halved
// load-queue depth lost ~8us/kernel) back to R13's 8-thr/node shape (212.6);
// add vectorized bucket-index reads (uint4 = 8 edges' indices per load,
// parity-extracted; rows are 128B-aligned) replacing ~8 scalar ushort loads.
// Eliminated-as-neutral on the gather: bytes (R9), traffic (R10), ILP/occ
// (R11), divergence (R12), depth-split (R14). Floors: ~46us 800k device
// atomics (K0), ~46us in-stream harness ws-poison, ~105us gather layers.

constexpr int HID = 48;
constexpr int MAXDEG = 64;
constexpr int GNB = 64;  // nodes per K0 proj block

__device__ __forceinline__ unsigned pack_h2(float a, float b) {
    __half2 h = __floats2half2_rn(a, b);
    return *reinterpret_cast<unsigned*>(&h);
}
__device__ __forceinline__ void acc_u2(float* g, uint2 u) {
    __half2 h0 = *reinterpret_cast<__half2*>(&u.x);
    __half2 h1 = *reinterpret_cast<__half2*>(&u.y);
    float2 f0 = __half22float2(h0), f1 = __half22float2(h1);
    g[0] += f0.x; g[1] += f0.y; g[2] += f1.x; g[3] += f1.y;
}
__device__ __forceinline__ void unpack_u2(float* v, uint2 u) {
    __half2 h0 = *reinterpret_cast<__half2*>(&u.x);
    __half2 h1 = *reinterpret_cast<__half2*>(&u.y);
    float2 f0 = __half22float2(h0), f1 = __half22float2(h1);
    v[0] = f0.x; v[1] = f0.y; v[2] = f1.x; v[3] = f1.y;
}
__device__ __forceinline__ void fma12_h(const uint2* __restrict__ wrow, float s,
                                        float* acc) {
    uint2 w0 = wrow[0], w1 = wrow[1], w2 = wrow[2];
    float v[12];
    unpack_u2(v + 0, w0); unpack_u2(v + 4, w1); unpack_u2(v + 8, w2);
#pragma unroll
    for (int j = 0; j < 12; ++j) acc[j] = fmaf(s, v[j], acc[j]);
}

// gather parity-e edges, slice jb; bucket indices read as uint4 (8 edges per
// 16B load, both parities broadcast-share it, extract by shift). 4 rows in
// flight per chunk; halves combined via shfl_xor(4) -> full sum in g[12].
__device__ __forceinline__ void gather_h4(const __half* __restrict__ p,
                                          const unsigned short* __restrict__ bkt,
                                          int deg, int e, int jb, float* g) {
    float ga[12], gb[12];
#pragma unroll
    for (int j = 0; j < 12; ++j) { ga[j] = 0.0f; gb[j] = 0.0f; }
    const uint4* b4 = reinterpret_cast<const uint4*>(bkt);
    const int sh = e * 16;
    const int nch = deg >> 3;          // full chunks of 8 edges
    for (int c = 0; c < nch; ++c) {
        uint4 bv = b4[c];
        int s0 = (bv.x >> sh) & 0xffff;
        int s1 = (bv.y >> sh) & 0xffff;
        int s2 = (bv.z >> sh) & 0xffff;
        int s3 = (bv.w >> sh) & 0xffff;
        const uint2* r0 = reinterpret_cast<const uint2*>(p + (size_t)s0 * HID + jb);
        const uint2* r1 = reinterpret_cast<const uint2*>(p + (size_t)s1 * HID + jb);
        const uint2* r2 = reinterpret_cast<const uint2*>(p + (size_t)s2 * HID + jb);
        const uint2* r3 = reinterpret_cast<const uint2*>(p + (size_t)s3 * HID + jb);
        uint2 a0 = r0[0], a1 = r0[1], a2 = r0[2];
        uint2 b0 = r1[0], b1 = r1[1], b2 = r1[2];
        uint2 c0 = r2[0], c1 = r2[1], c2 = r2[2];
        uint2 d0 = r3[0], d1 = r3[1], d2 = r3[2];
        acc_u2(ga + 0, a0); acc_u2(ga + 4, a1); acc_u2(ga + 8, a2);
        acc_u2(gb + 0, b0); acc_u2(gb + 4, b1); acc_u2(gb + 8, b2);
        acc_u2(ga + 0, c0); acc_u2(ga + 4, c1); acc_u2(ga + 8, c2);
        acc_u2(gb + 0, d0); acc_u2(gb + 4, d1); acc_u2(gb + 8, d2);
    }
    for (int i = nch * 8 + e; i < deg; i += 2) {
        const uint2* r0 = reinterpret_cast<const uint2*>(p + (size_t)bkt[i] * HID + jb);
        uint2 a0 = r0[0], a1 = r0[1], a2 = r0[2];
        acc_u2(ga + 0, a0); acc_u2(ga + 4, a1); acc_u2(ga + 8, a2);
    }
#pragma unroll
    for (int j = 0; j < 12; ++j) g[j] = ga[j] + gb[j];
#pragma unroll
    for (int j = 0; j < 12; ++j) g[j] += __shfl_xor(g[j], 4, 64);
}

// ---- K0: blocks [0,gemm_blocks): single pass, p0=fp16(X@Wn), s0=X@Ws+b,
//      fp16 weights in LDS; blocks [gemm_blocks,..): bucket fill ----
__global__ __launch_bounds__(128) void fill_proj_k(
    const float* __restrict__ X, const float* __restrict__ Wn,
    const float* __restrict__ Ws, const float* __restrict__ bias,
    __half* __restrict__ p_out, float* __restrict__ s_out, int n_nodes,
    const int* __restrict__ src, const int* __restrict__ dst,
    int* __restrict__ cnt, unsigned short* __restrict__ buckets,
    int n_edges, int gemm_blocks) {
    __shared__ uint2 wn_s[96 * HID / 4];   // 9.2 KB packed fp16
    __shared__ uint2 ws_s[96 * HID / 4];   // 9.2 KB
    __shared__ float bias_lds[HID];
    const int t = threadIdx.x;

    if ((int)blockIdx.x >= gemm_blocks) {
        int base = (blockIdx.x - gemm_blocks) * 256 + t;
        int e0 = base, e1 = base + 128;
        if (e0 < n_edges) {
            int d = dst[e0];
            int s = src[e0];
            int pos = atomicAdd(&cnt[d], 1);
            if (pos < MAXDEG) buckets[(size_t)d * MAXDEG + pos] = (unsigned short)s;
        }
        if (e1 < n_edges) {
            int d = dst[e1];
            int s = src[e1];
            int pos = atomicAdd(&cnt[d], 1);
            if (pos < MAXDEG) buckets[(size_t)d * MAXDEG + pos] = (unsigned short)s;
        }
        return;
    }

    for (int i4 = t; i4 < 96 * HID / 4; i4 += 128) {
        float4 a = reinterpret_cast<const float4*>(Wn)[i4];
        float4 b = reinterpret_cast<const float4*>(Ws)[i4];
        wn_s[i4] = make_uint2(pack_h2(a.x, a.y), pack_h2(a.z, a.w));
        ws_s[i4] = make_uint2(pack_h2(b.x, b.y), pack_h2(b.z, b.w));
    }
    if (t < HID) bias_lds[t] = bias[t];
    __syncthreads();

    const int q = t & 3;
    const int m = t >> 2;
    const int jb = q * 12;
    const int q3 = q * 3;
    const int n0 = blockIdx.x * GNB + 2 * m;
    const int n1 = n0 + 1;
    const bool v0 = n0 < n_nodes, v1 = n1 < n_nodes;
    const int cn0 = v0 ? n0 : 0, cn1 = v1 ? n1 : 0;
    const float4* xr0 = reinterpret_cast<const float4*>(X + (size_t)cn0 * 96);
    const float4* xr1 = reinterpret_cast<const float4*>(X + (size_t)cn1 * 96);

    float pa[12], pb[12], sa[12], sb[12];
#pragma unroll
    for (int j = 0; j < 12; ++j) {
        pa[j] = 0.0f; pb[j] = 0.0f;
        float b = bias_lds[jb + j];
        sa[j] = b; sb[j] = b;
    }
#pragma unroll 2
    for (int k4 = 0; k4 < 24; ++k4) {
        float4 xa = xr0[k4];
        float4 xb = xr1[k4];
#pragma unroll
        for (int c = 0; c < 4; ++c) {
            const int k = k4 * 4 + c;
            float x0 = (c == 0) ? xa.x : (c == 1) ? xa.y : (c == 2) ? xa.z : xa.w;
            float x1 = (c == 0) ? xb.x : (c == 1) ? xb.y : (c == 2) ? xb.z : xb.w;
            const uint2* wr = &wn_s[k * 12 + q3];
            const uint2* ur = &ws_s[k * 12 + q3];
            float vn[12], vs[12];
            uint2 w0 = wr[0], w1 = wr[1], w2 = wr[2];
            uint2 u0 = ur[0], u1 = ur[1], u2 = ur[2];
            unpack_u2(vn + 0, w0); unpack_u2(vn + 4, w1); unpack_u2(vn + 8, w2);
            unpack_u2(vs + 0, u0); unpack_u2(vs + 4, u1); unpack_u2(vs + 8, u2);
#pragma unroll
            for (int j = 0; j < 12; ++j) {
                pa[j] = fmaf(x0, vn[j], pa[j]);
                pb[j] = fmaf(x1, vn[j], pb[j]);
                sa[j] = fmaf(x0, vs[j], sa[j]);
                sb[j] = fmaf(x1, vs[j], sb[j]);
            }
        }
    }
    if (v0) {
        uint2* po = reinterpret_cast<uint2*>(p_out + (size_t)n0 * HID + jb);
        po[0] = make_uint2(pack_h2(pa[0], pa[1]), pack_h2(pa[2], pa[3]));
        po[1] = make_uint2(pack_h2(pa[4], pa[5]), pack_h2(pa[6], pa[7]));
        po[2] = make_uint2(pack_h2(pa[8], pa[9]), pack_h2(pa[10], pa[11]));
        float4* so = reinterpret_cast<float4*>(s_out + (size_t)n0 * HID + jb);
        so[0] = make_float4(sa[0], sa[1], sa[2], sa[3]);
        so[1] = make_float4(sa[4], sa[5], sa[6], sa[7]);
        so[2] = make_float4(sa[8], sa[9], sa[10], sa[11]);
    }
    if (v1) {
        uint2* po = reinterpret_cast<uint2*>(p_out + (size_t)n1 * HID + jb);
        po[0] = make_uint2(pack_h2(pb[0], pb[1]), pack_h2(pb[2], pb[3]));
        po[1] = make_uint2(pack_h2(pb[4], pb[5]), pack_h2(pb[6], pb[7]));
        po[2] = make_uint2(pack_h2(pb[8], pb[9]), pack_h2(pb[10], pb[11]));
        float4* so = reinterpret_cast<float4*>(s_out + (size_t)n1 * HID + jb);
        so[0] = make_float4(sb[0], sb[1], sb[2], sb[3]);
        so[1] = make_float4(sb[4], sb[5], sb[6], sb[7]);
        so[2] = make_float4(sb[8], sb[9], sb[10], sb[11]);
    }
}

// ---- K1: h1 = relu(s0 + di * mean-gather(p0)); fp16 out. 8 thr/node. ----
__global__ __launch_bounds__(128, 6) void act_k(
    const __half* __restrict__ p_in, const float* __restrict__ s_in,
    const int* __restrict__ cnt, const unsigned short* __restrict__ buckets,
    __half* __restrict__ h_out, int n_nodes) {
    const int t = threadIdx.x;
    const int q = t & 3;
    const int e = (t >> 2) & 1;
    const int m = t >> 3;
    const int n = blockIdx.x * 16 + m;
    if (n >= n_nodes) return;
    const int jb = q * 12;

    const int deg = min(cnt[n], MAXDEG);
    const float di = 1.0f / fmaxf((float)deg, 1.0f);
    float g[12];
    gather_h4(p_in, buckets + (size_t)n * MAXDEG, deg, e, jb, g);

    if (e == 0) {
        const float4* sr = reinterpret_cast<const float4*>(s_in + (size_t)n * HID + jb);
        float h[12];
#pragma unroll
        for (int j4 = 0; j4 < 3; ++j4) {
            float4 sv = sr[j4];
            h[j4 * 4 + 0] = fmaxf(fmaf(di, g[j4 * 4 + 0], sv.x), 0.0f);
            h[j4 * 4 + 1] = fmaxf(fmaf(di, g[j4 * 4 + 1], sv.y), 0.0f);
            h[j4 * 4 + 2] = fmaxf(fmaf(di, g[j4 * 4 + 2], sv.z), 0.0f);
            h[j4 * 4 + 3] = fmaxf(fmaf(di, g[j4 * 4 + 3], sv.w), 0.0f);
        }
        uint2* ho = reinterpret_cast<uint2*>(h_out + (size_t)n * HID + jb);
        ho[0] = make_uint2(pack_h2(h[0], h[1]), pack_h2(h[2], h[3]));
        ho[1] = make_uint2(pack_h2(h[4], h[5]), pack_h2(h[6], h[7]));
        ho[2] = make_uint2(pack_h2(h[8], h[9]), pack_h2(h[10], h[11]));
    }
}

// ---- K2/K3: g = mean-gather(h_in); acc = g@Wn + h_self@Ws + b (fp16 W in LDS).
template <bool LAST>
__global__ __launch_bounds__(128, 6) void layer_k(
    const __half* __restrict__ h_in, const int* __restrict__ cnt,
    const unsigned short* __restrict__ buckets, const float* __restrict__ wn,
    const float* __restrict__ ws, const float* __restrict__ bn,
    const float* __restrict__ w_pred, const float* __restrict__ b_pred,
    __half* __restrict__ h_out, float* __restrict__ out, int n_nodes) {
    __shared__ uint2 wn_s[HID * HID / 4];   // 4.6 KB packed fp16
    __shared__ uint2 ws_s[HID * HID / 4];   // 4.6 KB
    __shared__ float bn_lds[HID];
    __shared__ float wp_lds[HID];

    const int t = threadIdx.x;
    for (int i4 = t; i4 < HID * HID / 4; i4 += 128) {
        float4 a = reinterpret_cast<const float4*>(wn)[i4];
        float4 b = reinterpret_cast<const float4*>(ws)[i4];
        wn_s[i4] = make_uint2(pack_h2(a.x, a.y), pack_h2(a.z, a.w));
        ws_s[i4] = make_uint2(pack_h2(b.x, b.y), pack_h2(b.z, b.w));
    }
    if (t < HID) bn_lds[t] = bn[t];
    if (LAST && t < HID) wp_lds[t] = w_pred[t];
    __syncthreads();

    const int q = t & 3;
    const int e = (t >> 2) & 1;
    const int m = t >> 3;
    const int n = blockIdx.x * 16 + m;
    if (n >= n_nodes) return;
    const int jb = q * 12;

    const int deg = min(cnt[n], MAXDEG);
    const float di = 1.0f / fmaxf((float)deg, 1.0f);
    float g[12];
    gather_h4(h_in, buckets + (size_t)n * MAXDEG, deg, e, jb, g);
#pragma unroll
    for (int j = 0; j < 12; ++j) g[j] *= di;

    float hs_own[12];
    {
        const uint2* hr = reinterpret_cast<const uint2*>(h_in + (size_t)n * HID + jb);
        uint2 a = hr[0], b = hr[1], c = hr[2];
        unpack_u2(hs_own + 0, a); unpack_u2(hs_own + 4, b); unpack_u2(hs_own + 8, c);
    }

    float acc[12];
#pragma unroll
    for (int j = 0; j < 12; ++j) acc[j] = (e == 0) ? bn_lds[jb + j] : 0.0f;

    const int kb = e * 24;
#pragma unroll
    for (int kk = 0; kk < 24; ++kk) {
        const int k = kb + kk;
        const int srcl = (t & ~3) | (k / 12);
        float gs = __shfl(g[kk % 12], srcl, 64);
        float hv = __shfl(hs_own[kk % 12], srcl, 64);
        fma12_h(&wn_s[(k * HID + jb) >> 2], gs, acc);
        fma12_h(&ws_s[(k * HID + jb) >> 2], hv, acc);
    }
#pragma unroll
    for (int j = 0; j < 12; ++j) acc[j] += __shfl_xor(acc[j], 4, 64);

    if (LAST) {
        float s = 0.0f;
#pragma unroll
        for (int j = 0; j < 12; ++j) s = fmaf(fmaxf(acc[j], 0.0f), wp_lds[jb + j], s);
        s += __shfl_xor(s, 1, 64);
        s += __shfl_xor(s, 2, 64);
        if ((t & 7) == 0) out[n] = s + b_pred[0];
        return;
    }

    if (e == 0) {
        float h[12];
#pragma unroll
        for (int j = 0; j < 12; ++j) h[j] = fmaxf(acc[j], 0.0f);
        uint2* ho = reinterpret_cast<uint2*>(h_out + (size_t)n * HID + jb);
        ho[0] = make_uint2(pack_h2(h[0], h[1]), pack_h2(h[2], h[3]));
        ho[1] = make_uint2(pack_h2(h[4], h[5]), pack_h2(h[6], h[7]));
        ho[2] = make_uint2(pack_h2(h[8], h[9]), pack_h2(h[10], h[11]));
    }
}

extern "C" void kernel_launch(void* const* d_in, const int* in_sizes, int n_in,
                              void* d_out, int out_size, void* d_ws, size_t ws_size,
                              hipStream_t stream) {
    const float* x        = (const float*)d_in[0];
    const int*   ei       = (const int*)d_in[1];
    const float* w_self0  = (const float*)d_in[2];
    const float* w_neigh0 = (const float*)d_in[3];
    const float* b0       = (const float*)d_in[4];
    const float* w_self1  = (const float*)d_in[5];
    const float* w_neigh1 = (const float*)d_in[6];
    const float* b1       = (const float*)d_in[7];
    const float* w_self2  = (const float*)d_in[8];
    const float* w_neigh2 = (const float*)d_in[9];
    const float* b2       = (const float*)d_in[10];
    const float* w_pred   = (const float*)d_in[11];
    const float* b_pred   = (const float*)d_in[12];

    const int n_nodes = in_sizes[0] / 96;
    const int n_edges = in_sizes[1] / 2;
    const int* src = ei;
    const int* dst = ei + n_edges;

    // workspace layout
    char* wsb = (char*)d_ws;
    int* cnt                = (int*)wsb;              wsb += (size_t)n_nodes * 4;
    unsigned short* buckets = (unsigned short*)wsb;   wsb += (size_t)n_nodes * MAXDEG * 2;
    __half* p0 = (__half*)wsb;                        wsb += (size_t)n_nodes * HID * 2;
    __half* h1 = (__half*)wsb;                        wsb += (size_t)n_nodes * HID * 2;
    __half* h2 = (__half*)wsb;                        wsb += (size_t)n_nodes * HID * 2;
    float* s0 = (float*)wsb;                          wsb += (size_t)n_nodes * HID * 4;
    float* out = (float*)d_out;

    const int gnb = (n_nodes + GNB - 1) / GNB;        // 782 proj blocks
    const int fb = (n_edges + 255) / 256;             // 3125 fill blocks
    const int lb = (n_nodes + 15) / 16;               // 3125 layer blocks

    hipMemsetAsync(cnt, 0, (size_t)n_nodes * 4, stream);

    // K0: fill + p0(fp16), s0 (single pass, fp16 weights)
    fill_proj_k<<<gnb + fb, 128, 0, stream>>>(x, w_neigh0, w_self0, b0, p0, s0,
                                              n_nodes, src, dst, cnt, buckets,
                                              n_edges, gnb);
    // K1: h1 = relu(s0 + di*gather(p0))
    act_k<<<lb, 128, 0, stream>>>(p0, s0, cnt, buckets, h1, n_nodes);
    // K2: layer 1 -> h2
    layer_k<false><<<lb, 128, 0, stream>>>(h1, cnt, buckets, w_neigh1, w_self1,
                                           b1, nullptr, nullptr, h2, nullptr,
                                           n_nodes);
    // K3: layer 2 + head -> out
    layer_k<true><<<lb, 128, 0, stream>>>(h2, cnt, buckets, w_neigh2, w_self2,
                                          b2, w_pred, b_pred, nullptr, out,
                                          n_nodes);
}